// Round 3
// baseline (75.753 us; speedup 1.0000x reference)
//
#include <hip/hip_runtime.h>

typedef __attribute__((ext_vector_type(8))) short short8;
typedef __attribute__((ext_vector_type(4))) float f32x4;

#define MFMA(a, b, c) __builtin_amdgcn_mfma_f32_16x16x32_bf16(a, b, c, 0, 0, 0)

__device__ __forceinline__ unsigned short f2bf16(float f) {
    __bf16 h = (__bf16)f;
    return __builtin_bit_cast(unsigned short, h);
}
__device__ __forceinline__ unsigned pk2(float a, float b) {
    return (unsigned)f2bf16(a) | ((unsigned)f2bf16(b) << 16);
}

// ---------------- prep: weights -> MFMA A-fragment order (bf16), BN folded ----------------
// w1a: [16 mtiles][64 lanes][8]  A[o][k], o=mt*16+(lane&15), k=(lane>>4)*8+e
//      k<27: w1*inv ; k==27: folded bias (input channel k=27 is constant 1.0) ; else 0
// w2a: [kt*8+mt][64][8]          A[o][k], o=mt*16+(lane&15), k=kt*32+(lane>>4)*8+e
// w3a: [kt][64][8]               A[o][k], o=lane&15,         k=kt*32+(lane>>4)*8+e
__global__ void prep_kernel(const float* __restrict__ w1, const float* __restrict__ b1,
                            const float* __restrict__ gamma, const float* __restrict__ beta,
                            const float* __restrict__ mean, const float* __restrict__ var,
                            const float* __restrict__ w2, const float* __restrict__ w3,
                            unsigned short* __restrict__ w1a, unsigned short* __restrict__ w2a,
                            unsigned short* __restrict__ w3a) {
    int idx = blockIdx.x * 256 + threadIdx.x;
    if (idx < 8192) {
        int mt = idx >> 9, r = idx & 511, lane = r >> 3, e = r & 7;
        int o = mt * 16 + (lane & 15);
        int k = ((lane >> 4) << 3) + e;
        float inv = gamma[o] * rsqrtf(var[o] + 1e-5f);
        float v;
        if (k < 27)       v = w1[o * 27 + k] * inv;
        else if (k == 27) v = b1[o] * inv + beta[o] - mean[o] * inv;
        else              v = 0.0f;
        w1a[idx] = f2bf16(v);
    }
    if (idx < 32768) {
        int tile = idx >> 9, r = idx & 511, lane = r >> 3, e = r & 7;
        int kt = tile >> 3, mt = tile & 7;
        int o = mt * 16 + (lane & 15);
        int k = kt * 32 + ((lane >> 4) << 3) + e;
        w2a[idx] = f2bf16(w2[o * 256 + k]);
    }
    if (idx < 2048) {
        int kt = idx >> 9, r = idx & 511, lane = r >> 3, e = r & 7;
        int o = lane & 15;
        int k = kt * 32 + ((lane >> 4) << 3) + e;
        w3a[idx] = f2bf16(w3[o * 128 + k]);
    }
}

// ---------------- main: one 16x16 block (even block-col only) per workgroup ----------------
// 2048 blocks x 256 threads (4 waves). Each wave owns 64 pixels (4 spatial rows)
// end-to-end: no inter-wave barriers except patch staging and the final pool.
__global__ __launch_bounds__(256, 2)
void fused_block_kernel(const float* __restrict__ x,
                        const unsigned short* __restrict__ w1a,
                        const unsigned short* __restrict__ w2a,
                        const unsigned short* __restrict__ w3a,
                        const float* __restrict__ b2, const float* __restrict__ b3,
                        float* __restrict__ out) {
    __shared__ __align__(16) unsigned short patch[3 * 18 * 18];
    __shared__ __align__(16) unsigned short chunk[4][64 * 40];  // per-wave [px][och32 pad40]
    __shared__ float poolW[4][16];
    __shared__ float poolF[16];

    int tid = threadIdx.x;
    int bid = blockIdx.x;
    int b  = bid >> 9;
    int br = (bid >> 4) & 31;
    int j  = bid & 15;            // block col = 2*j (only even block-cols feed the output)
    int r0 = br * 16;
    int c0 = j * 32;
    int lane = tid & 63;
    int w = tid >> 6;
    int g = lane >> 4;            // lane group 0..3
    int c = lane & 15;            // column within fragment

    // ---- stage x patch (3ch x 18x18, SAME zero-pad) -> bf16 ----
    for (int i = tid; i < 972; i += 256) {
        int ch = i / 324, rr = (i % 324) / 18, cc = i % 18;
        int gr = r0 + rr - 1, gc = c0 + cc - 1;
        float v = 0.0f;
        if ((unsigned)gr < 512u && (unsigned)gc < 512u)
            v = x[((b * 3 + ch) * 512 + gr) * 512 + gc];
        patch[i] = f2bf16(v);
    }
    __syncthreads();

    // ---- im2col offsets for this lane's k-octet (k = g*8+e) ----
    int offk[8];
    #pragma unroll
    for (int e = 0; e < 8; e++) {
        int k = g * 8 + e;
        int ch = (k * 7282) >> 16;       // k/9 for k<32
        int rem = k - ch * 9;
        int dy = (rem * 21846) >> 16;    // rem/3
        int dx = rem - dy * 3;
        int o = ch * 324 + dy * 18 + dx;
        offk[e] = (k < 27) ? o : 0;
    }

    // ---- build GEMM1 B-fragments directly in registers (held all kernel) ----
    short8 bfr[4];
    #pragma unroll
    for (int nj = 0; nj < 4; nj++) {
        int base = (4 * w + nj) * 18 + c;
        unsigned val[8];
        #pragma unroll
        for (int e = 0; e < 8; e++)
            val[e] = patch[base + offk[e]];
        if (g == 3) {                    // k=27 -> bias channel 1.0 ; k>27 -> 0
            val[3] = 0x3F80u;
            val[4] = val[5] = val[6] = val[7] = 0u;
        }
        union { unsigned u[4]; short8 s; } uu;
        #pragma unroll
        for (int q = 0; q < 4; q++)
            uu.u[q] = val[2 * q] | (val[2 * q + 1] << 16);
        bfr[nj] = uu.s;
    }

    unsigned short* ck = &chunk[w][0];
    int rdo[4], wbo[4];
    #pragma unroll
    for (int nj = 0; nj < 4; nj++) {
        int px = nj * 16 + c;
        rdo[nj] = px * 40 + g * 8;       // b128 read: och_local = g*8..g*8+7
        wbo[nj] = px * 40 + g * 4;       // b64 write: och_local = h*16 + g*4..+3
    }

    f32x4 acc2[8][4];
    #pragma unroll
    for (int m = 0; m < 8; m++)
        #pragma unroll
        for (int nj = 0; nj < 4; nj++)
            acc2[m][nj] = (f32x4){0.f, 0.f, 0.f, 0.f};

    const f32x4 zero = {0.f, 0.f, 0.f, 0.f};

    // ---- fused GEMM1 -> GEMM2 over 8 k-chunks of 32 feat channels ----
    #pragma unroll
    for (int kt = 0; kt < 8; kt++) {
        // GEMM1 chunk: feat[kt*32 .. +32)[64 px], relu, -> chunk LDS
        #pragma unroll
        for (int h = 0; h < 2; h++) {
            short8 w1f = *(const short8*)&w1a[(kt * 2 + h) * 512 + lane * 8];
            #pragma unroll
            for (int nj = 0; nj < 4; nj++) {
                f32x4 a = MFMA(w1f, bfr[nj], zero);
                uint2 pk;
                pk.x = pk2(fmaxf(a[0], 0.f), fmaxf(a[1], 0.f));
                pk.y = pk2(fmaxf(a[2], 0.f), fmaxf(a[3], 0.f));
                *(uint2*)&ck[wbo[nj] + h * 16] = pk;
            }
        }
        // read back as B-frags (same wave; DS pipe is in-order)
        short8 b2f[4];
        #pragma unroll
        for (int nj = 0; nj < 4; nj++)
            b2f[nj] = *(const short8*)&ck[rdo[nj]];
        // GEMM2 partial: all 128 h-channels for this wave's 64 px
        #pragma unroll
        for (int m = 0; m < 8; m++) {
            short8 w2f = *(const short8*)&w2a[(kt * 8 + m) * 512 + lane * 8];
            #pragma unroll
            for (int nj = 0; nj < 4; nj++)
                acc2[m][nj] = MFMA(w2f, b2f[nj], acc2[m][nj]);
        }
    }

    // ---- GEMM3: logits[16][64 px], K=128 over h in 4 chunks of 32 ----
    f32x4 b2r[8];
    #pragma unroll
    for (int m = 0; m < 8; m++)
        b2r[m] = *(const f32x4*)&b2[m * 16 + g * 4];
    f32x4 accP[4];
    #pragma unroll
    for (int nj = 0; nj < 4; nj++) accP[nj] = zero;

    #pragma unroll
    for (int kt = 0; kt < 4; kt++) {
        short8 w3f = *(const short8*)&w3a[kt * 512 + lane * 8];
        #pragma unroll
        for (int h = 0; h < 2; h++) {
            int m = kt * 2 + h;
            #pragma unroll
            for (int nj = 0; nj < 4; nj++) {
                uint2 pk;
                pk.x = pk2(fmaxf(acc2[m][nj][0] + b2r[m][0], 0.f),
                           fmaxf(acc2[m][nj][1] + b2r[m][1], 0.f));
                pk.y = pk2(fmaxf(acc2[m][nj][2] + b2r[m][2], 0.f),
                           fmaxf(acc2[m][nj][3] + b2r[m][3], 0.f));
                *(uint2*)&ck[wbo[nj] + h * 16] = pk;
            }
        }
        #pragma unroll
        for (int nj = 0; nj < 4; nj++) {
            short8 b3f = *(const short8*)&ck[rdo[nj]];
            accP[nj] = MFMA(w3f, b3f, accP[nj]);
        }
    }

    // ---- pool: sum logits over the wave's 64 px, then across waves ----
    float v0 = accP[0][0] + accP[1][0] + accP[2][0] + accP[3][0];
    float v1 = accP[0][1] + accP[1][1] + accP[2][1] + accP[3][1];
    float v2 = accP[0][2] + accP[1][2] + accP[2][2] + accP[3][2];
    float v3 = accP[0][3] + accP[1][3] + accP[2][3] + accP[3][3];
    #pragma unroll
    for (int off = 1; off < 16; off <<= 1) {
        v0 += __shfl_xor(v0, off);
        v1 += __shfl_xor(v1, off);
        v2 += __shfl_xor(v2, off);
        v3 += __shfl_xor(v3, off);
    }
    if (c == 0) {
        poolW[w][g * 4 + 0] = v0;
        poolW[w][g * 4 + 1] = v1;
        poolW[w][g * 4 + 2] = v2;
        poolW[w][g * 4 + 3] = v3;
    }
    __syncthreads();
    if (tid < 16) {
        float s = poolW[0][tid] + poolW[1][tid] + poolW[2][tid] + poolW[3][tid];
        poolF[tid] = s * (1.0f / 256.0f) + b3[tid];
    }
    __syncthreads();

    // ---- broadcast store: out[b][cc][h=br*16+j][:] = poolF[cc] ----
    int h = r0 + j;
    int cc = tid >> 4;
    float pv = poolF[cc];
    float4 vv = {pv, pv, pv, pv};
    float4* rowp = (float4*)(out + (size_t)(((b * 16 + cc) * 512 + h)) * 512);
    int base = tid & 15;
    #pragma unroll
    for (int ii = 0; ii < 8; ii++)
        rowp[ii * 16 + base] = vv;
}

extern "C" void kernel_launch(void* const* d_in, const int* in_sizes, int n_in,
                              void* d_out, int out_size, void* d_ws, size_t ws_size,
                              hipStream_t stream) {
    const float* x     = (const float*)d_in[0];
    const float* w1    = (const float*)d_in[1];
    const float* b1    = (const float*)d_in[2];
    const float* gamma = (const float*)d_in[3];
    const float* beta  = (const float*)d_in[4];
    const float* mean  = (const float*)d_in[5];
    const float* var   = (const float*)d_in[6];
    const float* w2    = (const float*)d_in[7];
    const float* b2    = (const float*)d_in[8];
    const float* w3    = (const float*)d_in[9];
    const float* b3    = (const float*)d_in[10];
    float* out = (float*)d_out;

    unsigned short* w1a = (unsigned short*)d_ws;        // 8192 bf16
    unsigned short* w2a = w1a + 8192;                   // 32768 bf16
    unsigned short* w3a = w2a + 32768;                  // 2048 bf16

    prep_kernel<<<128, 256, 0, stream>>>(w1, b1, gamma, beta, mean, var, w2, w3,
                                         w1a, w2a, w3a);
    fused_block_kernel<<<2048, 256, 0, stream>>>(x, w1a, w2a, w3a, b2, b3, out);
}

// Round 4
// 70.540 us; speedup vs baseline: 1.0739x; 1.0739x over previous
//
#include <hip/hip_runtime.h>

typedef __attribute__((ext_vector_type(8))) short short8;
typedef __attribute__((ext_vector_type(4))) float f32x4;

#define MFMA(a, b, c) __builtin_amdgcn_mfma_f32_16x16x32_bf16(a, b, c, 0, 0, 0)

__device__ __forceinline__ unsigned short f2bf16(float f) {
    __bf16 h = (__bf16)f;
    return __builtin_bit_cast(unsigned short, h);
}

// one-instruction packed f32x2 -> bf16x2 (RNE). D[15:0]=cvt(lo), D[31:16]=cvt(hi)
__device__ __forceinline__ unsigned cvtpk(float lo, float hi) {
    unsigned r;
    asm("v_cvt_pk_bf16_f32 %0, %1, %2" : "=v"(r) : "v"(lo), "v"(hi));
    return r;
}

// ---------------- prep: weights -> MFMA A-fragment order (bf16), BN folded ----------------
__global__ void prep_kernel(const float* __restrict__ w1, const float* __restrict__ b1,
                            const float* __restrict__ gamma, const float* __restrict__ beta,
                            const float* __restrict__ mean, const float* __restrict__ var,
                            const float* __restrict__ w2, const float* __restrict__ w3,
                            unsigned short* __restrict__ w1a, unsigned short* __restrict__ w2a,
                            unsigned short* __restrict__ w3a) {
    int idx = blockIdx.x * 256 + threadIdx.x;
    if (idx < 8192) {
        int mt = idx >> 9, r = idx & 511, lane = r >> 3, e = r & 7;
        int o = mt * 16 + (lane & 15);
        int k = ((lane >> 4) << 3) + e;
        float inv = gamma[o] * rsqrtf(var[o] + 1e-5f);
        float v;
        if (k < 27)       v = w1[o * 27 + k] * inv;
        else if (k == 27) v = b1[o] * inv + beta[o] - mean[o] * inv;
        else              v = 0.0f;
        w1a[idx] = f2bf16(v);
    }
    if (idx < 32768) {
        int tile = idx >> 9, r = idx & 511, lane = r >> 3, e = r & 7;
        int kt = tile >> 3, mt = tile & 7;
        int o = mt * 16 + (lane & 15);
        int k = kt * 32 + ((lane >> 4) << 3) + e;
        w2a[idx] = f2bf16(w2[o * 256 + k]);
    }
    if (idx < 2048) {
        int kt = idx >> 9, r = idx & 511, lane = r >> 3, e = r & 7;
        int o = lane & 15;
        int k = kt * 32 + ((lane >> 4) << 3) + e;
        w3a[idx] = f2bf16(w3[o * 128 + k]);
    }
}

// ---------------- main: one 16x16 block (even block-col only) per workgroup ----------------
// 2048 blocks x 256 threads (4 waves). Wave owns 64 px end-to-end; chunk is
// double-buffered so GEMM1(kt+1) schedules against GEMM2(kt)'s lgkm wait.
__global__ __launch_bounds__(256, 2)
void fused_block_kernel(const float* __restrict__ x,
                        const unsigned short* __restrict__ w1a,
                        const unsigned short* __restrict__ w2a,
                        const unsigned short* __restrict__ w3a,
                        const float* __restrict__ b2, const float* __restrict__ b3,
                        float* __restrict__ out) {
    __shared__ __align__(16) unsigned short patch[3 * 18 * 18];
    __shared__ __align__(16) unsigned short chunk[4][2][64 * 40];  // per-wave dbuf [px][och32 pad40]
    __shared__ float poolW[4][16];
    __shared__ float poolF[16];

    int tid = threadIdx.x;
    int bid = blockIdx.x;
    int b  = bid >> 9;
    int br = (bid >> 4) & 31;
    int j  = bid & 15;            // block col = 2*j (only even block-cols feed the output)
    int r0 = br * 16;
    int c0 = j * 32;
    int lane = tid & 63;
    int w = tid >> 6;
    int g = lane >> 4;            // lane group 0..3
    int c = lane & 15;            // column within fragment

    // ---- stage x patch (3ch x 18x18, SAME zero-pad) -> bf16 ----
    for (int i = tid; i < 972; i += 256) {
        int ch = i / 324, rr = (i % 324) / 18, cc = i % 18;
        int gr = r0 + rr - 1, gc = c0 + cc - 1;
        float v = 0.0f;
        if ((unsigned)gr < 512u && (unsigned)gc < 512u)
            v = x[((b * 3 + ch) * 512 + gr) * 512 + gc];
        patch[i] = f2bf16(v);
    }
    __syncthreads();

    // ---- im2col offsets for this lane's k-octet (k = g*8+e) ----
    int offk[8];
    #pragma unroll
    for (int e = 0; e < 8; e++) {
        int k = g * 8 + e;
        int ch = (k * 7282) >> 16;
        int rem = k - ch * 9;
        int dy = (rem * 21846) >> 16;
        int dx = rem - dy * 3;
        int o = ch * 324 + dy * 18 + dx;
        offk[e] = (k < 27) ? o : 0;
    }

    // ---- build GEMM1 B-fragments directly in registers (held all kernel) ----
    short8 bfr[4];
    #pragma unroll
    for (int nj = 0; nj < 4; nj++) {
        int base = (4 * w + nj) * 18 + c;
        unsigned val[8];
        #pragma unroll
        for (int e = 0; e < 8; e++)
            val[e] = patch[base + offk[e]];
        if (g == 3) {                    // k=27 -> bias channel 1.0 ; k>27 -> 0
            val[3] = 0x3F80u;
            val[4] = val[5] = val[6] = val[7] = 0u;
        }
        union { unsigned u[4]; short8 s; } uu;
        #pragma unroll
        for (int q = 0; q < 4; q++)
            uu.u[q] = val[2 * q] | (val[2 * q + 1] << 16);
        bfr[nj] = uu.s;
    }

    unsigned short* ck = &chunk[w][0][0];
    int rdo[4], wbo[4];
    #pragma unroll
    for (int nj = 0; nj < 4; nj++) {
        int px = nj * 16 + c;
        rdo[nj] = px * 40 + g * 8;       // b128 read
        wbo[nj] = px * 40 + g * 4;       // b64 write
    }

    f32x4 acc2[8][4];
    #pragma unroll
    for (int m = 0; m < 8; m++)
        #pragma unroll
        for (int nj = 0; nj < 4; nj++)
            acc2[m][nj] = (f32x4){0.f, 0.f, 0.f, 0.f};

    const f32x4 zero = {0.f, 0.f, 0.f, 0.f};

    // ---- produce feat chunk kt into dst ----
    #define PRODUCE(kt, dst)                                                     \
        {                                                                        \
            _Pragma("unroll")                                                    \
            for (int h = 0; h < 2; h++) {                                        \
                short8 w1f = *(const short8*)&w1a[((kt) * 2 + h) * 512 + lane * 8]; \
                _Pragma("unroll")                                                \
                for (int nj = 0; nj < 4; nj++) {                                 \
                    f32x4 a = MFMA(w1f, bfr[nj], zero);                          \
                    uint2 pk;                                                    \
                    pk.x = cvtpk(fmaxf(a[0], 0.f), fmaxf(a[1], 0.f));            \
                    pk.y = cvtpk(fmaxf(a[2], 0.f), fmaxf(a[3], 0.f));            \
                    *(uint2*)&(dst)[wbo[nj] + h * 16] = pk;                      \
                }                                                                \
            }                                                                    \
        }

    // ---- fused GEMM1 -> GEMM2 over 8 k-chunks, software-pipelined via dbuf ----
    PRODUCE(0, ck)
    #pragma unroll
    for (int kt = 0; kt < 8; kt++) {
        unsigned short* src = ck + (kt & 1) * 2560;
        unsigned short* dst = ck + ((kt + 1) & 1) * 2560;
        short8 b2f[4];
        #pragma unroll
        for (int nj = 0; nj < 4; nj++)
            b2f[nj] = *(const short8*)&src[rdo[nj]];
        if (kt < 7) PRODUCE(kt + 1, dst)
        #pragma unroll
        for (int m = 0; m < 8; m++) {
            short8 w2f = *(const short8*)&w2a[(kt * 8 + m) * 512 + lane * 8];
            #pragma unroll
            for (int nj = 0; nj < 4; nj++)
                acc2[m][nj] = MFMA(w2f, b2f[nj], acc2[m][nj]);
        }
    }

    // ---- GEMM3: logits[16][64 px], K=128 over h in 4 chunks of 32, dbuf'd ----
    f32x4 b2r[8];
    #pragma unroll
    for (int m = 0; m < 8; m++)
        b2r[m] = *(const f32x4*)&b2[m * 16 + g * 4];
    short8 w3f[4];
    #pragma unroll
    for (int kt = 0; kt < 4; kt++)
        w3f[kt] = *(const short8*)&w3a[kt * 512 + lane * 8];

    #define PRODUCE3(kt, dst)                                                    \
        {                                                                        \
            _Pragma("unroll")                                                    \
            for (int h = 0; h < 2; h++) {                                        \
                int m = (kt) * 2 + h;                                            \
                _Pragma("unroll")                                                \
                for (int nj = 0; nj < 4; nj++) {                                 \
                    uint2 pk;                                                    \
                    pk.x = cvtpk(fmaxf(acc2[m][nj][0] + b2r[m][0], 0.f),         \
                                 fmaxf(acc2[m][nj][1] + b2r[m][1], 0.f));        \
                    pk.y = cvtpk(fmaxf(acc2[m][nj][2] + b2r[m][2], 0.f),         \
                                 fmaxf(acc2[m][nj][3] + b2r[m][3], 0.f));        \
                    *(uint2*)&(dst)[wbo[nj] + h * 16] = pk;                      \
                }                                                                \
            }                                                                    \
        }

    f32x4 accP[2] = {zero, zero};
    PRODUCE3(0, ck)
    #pragma unroll
    for (int kt = 0; kt < 4; kt++) {
        unsigned short* src = ck + (kt & 1) * 2560;
        unsigned short* dst = ck + ((kt + 1) & 1) * 2560;
        short8 b3f[4];
        #pragma unroll
        for (int nj = 0; nj < 4; nj++)
            b3f[nj] = *(const short8*)&src[rdo[nj]];
        if (kt < 3) PRODUCE3(kt + 1, dst)
        #pragma unroll
        for (int nj = 0; nj < 4; nj++)
            accP[kt & 1] = MFMA(w3f[kt], b3f[nj], accP[kt & 1]);
    }

    // ---- pool: sum logits over the wave's 64 px, then across waves ----
    float v0 = accP[0][0] + accP[1][0];
    float v1 = accP[0][1] + accP[1][1];
    float v2 = accP[0][2] + accP[1][2];
    float v3 = accP[0][3] + accP[1][3];
    #pragma unroll
    for (int off = 1; off < 16; off <<= 1) {
        v0 += __shfl_xor(v0, off);
        v1 += __shfl_xor(v1, off);
        v2 += __shfl_xor(v2, off);
        v3 += __shfl_xor(v3, off);
    }
    if (c == 0) {
        poolW[w][g * 4 + 0] = v0;
        poolW[w][g * 4 + 1] = v1;
        poolW[w][g * 4 + 2] = v2;
        poolW[w][g * 4 + 3] = v3;
    }
    __syncthreads();
    if (tid < 16) {
        float s = poolW[0][tid] + poolW[1][tid] + poolW[2][tid] + poolW[3][tid];
        poolF[tid] = s * (1.0f / 256.0f) + b3[tid];
    }
    __syncthreads();

    // ---- broadcast store: out[b][cc][h=br*16+j][:] = poolF[cc] ----
    int h = r0 + j;
    int cc = tid >> 4;
    float pv = poolF[cc];
    float4 vv = {pv, pv, pv, pv};
    float4* rowp = (float4*)(out + (size_t)(((b * 16 + cc) * 512 + h)) * 512);
    int base = tid & 15;
    #pragma unroll
    for (int ii = 0; ii < 8; ii++)
        rowp[ii * 16 + base] = vv;
}

extern "C" void kernel_launch(void* const* d_in, const int* in_sizes, int n_in,
                              void* d_out, int out_size, void* d_ws, size_t ws_size,
                              hipStream_t stream) {
    const float* x     = (const float*)d_in[0];
    const float* w1    = (const float*)d_in[1];
    const float* b1    = (const float*)d_in[2];
    const float* gamma = (const float*)d_in[3];
    const float* beta  = (const float*)d_in[4];
    const float* mean  = (const float*)d_in[5];
    const float* var   = (const float*)d_in[6];
    const float* w2    = (const float*)d_in[7];
    const float* b2    = (const float*)d_in[8];
    const float* w3    = (const float*)d_in[9];
    const float* b3    = (const float*)d_in[10];
    float* out = (float*)d_out;

    unsigned short* w1a = (unsigned short*)d_ws;        // 8192 bf16
    unsigned short* w2a = w1a + 8192;                   // 32768 bf16
    unsigned short* w3a = w2a + 32768;                  // 2048 bf16

    prep_kernel<<<128, 256, 0, stream>>>(w1, b1, gamma, beta, mean, var, w2, w3,
                                         w1a, w2a, w3a);
    fused_block_kernel<<<2048, 256, 0, stream>>>(x, w1a, w2a, w3a, b2, b3, out);
}